// Round 7
// baseline (89.182 us; speedup 1.0000x reference)
//
#include <hip/hip_runtime.h>
#include <hip/hip_bf16.h>

#define N_SAMPLES 4096
#define DIM 512
#define BM 64
#define BK 64
#define NK (DIM / BK)                 // 8 K-steps
#define NBT (N_SAMPLES / BM)          // 64 tiles per dim
#define NTILES (NBT * (NBT + 1) / 2)  // 2080 upper-triangle tiles

typedef __attribute__((ext_vector_type(8))) short short8;
typedef __attribute__((ext_vector_type(4))) float floatx4;

__device__ __forceinline__ void gload_lds16(const void* gptr, void* lptr) {
    __builtin_amdgcn_global_load_lds(
        (const __attribute__((address_space(1))) void*)gptr,
        (__attribute__((address_space(3))) void*)lptr, 16, 0, 0);
}

__device__ __forceinline__ short bf16bits(float x) {
    __hip_bfloat16 h = __float2bfloat16(x);
    return *reinterpret_cast<short*>(&h);
}

// ---------------------------------------------------------------------------
// Kernel 1: row L2-normalize fp32 -> bf16 G. One wave per row (no barriers).
// Also zeroes row_sum/pos_sum and the done counter.
// ---------------------------------------------------------------------------
__global__ __launch_bounds__(512) void scl_normalize(
    const float* __restrict__ F, __hip_bfloat16* __restrict__ G,
    float* __restrict__ row_sum, float* __restrict__ pos_sum,
    unsigned int* __restrict__ done)
{
    const int t = threadIdx.x;
    const int lane = t & 63;
    const int row = blockIdx.x * 8 + (t >> 6);
    const float4* fr = (const float4*)(F + (size_t)row * DIM);
    float4 va = fr[lane * 2];
    float4 vb = fr[lane * 2 + 1];
    float ss = va.x * va.x + va.y * va.y + va.z * va.z + va.w * va.w +
               vb.x * vb.x + vb.y * vb.y + vb.z * vb.z + vb.w * vb.w;
    #pragma unroll
    for (int off = 1; off < 64; off <<= 1) ss += __shfl_xor(ss, off);
    float inv = ss > 0.f ? 1.0f / sqrtf(ss) : 0.f;
    short8 h;
    h[0] = bf16bits(va.x * inv); h[1] = bf16bits(va.y * inv);
    h[2] = bf16bits(va.z * inv); h[3] = bf16bits(va.w * inv);
    h[4] = bf16bits(vb.x * inv); h[5] = bf16bits(vb.y * inv);
    h[6] = bf16bits(vb.z * inv); h[7] = bf16bits(vb.w * inv);
    ((short8*)((short*)G + (size_t)row * DIM))[lane] = h;
    if (lane == 0) { row_sum[row] = 0.f; pos_sum[row] = 0.f; }
    if (t == 0 && blockIdx.x == 0) *done = 0u;
}

// ---------------------------------------------------------------------------
// Kernel 2: upper-triangle tile (bi<=bj) of S = G*G^T, 64x64 tiles.
// Round-2 double-buffered pipeline shrunk to 64^2: grid = 2080 blocks
// (8.1/CU -> real co-residency; rounds 1-6 were stuck at 2.06 blocks/CU
// with 528 blocks, occupancy ~9-19%, latency-bound). LDS 32 KB (dbuf),
// acc[2][2] -> light VGPR. XOR-swizzled LDS (linear gload_lds dest +
// XOR'd global source chunk + XOR'd ds_read; ~0 conflicts measured).
// 4 waves (2x2), wave tile 32x32. Epilogue: exp + row sums (+ col sums
// off-diag, S symmetric). Finalize fused via last-block-done.
// ---------------------------------------------------------------------------
__global__ __launch_bounds__(256) void scl_gemm_epilogue(
    const __hip_bfloat16* __restrict__ G,
    const int* __restrict__ labels,
    float* __restrict__ row_sum,
    float* __restrict__ pos_sum,
    unsigned int* __restrict__ done,
    float* __restrict__ out)
{
    __shared__ __align__(16) short As[2][BM * BK];   // 2 x 8 KB
    __shared__ __align__(16) short Bs[2][BM * BK];   // 2 x 8 KB -> 32 KB total

    const int t = threadIdx.x;
    const int lane = t & 63;
    const int q = lane >> 4;            // quarter-group 0..3 (k-chunk)
    const int wid = t >> 6;             // 0..3
    const int wr = wid >> 1;            // wave row 0..1 (32 rows)
    const int wc = wid & 1;             // wave col 0..1 (32 cols)

    // XCD-chunked swizzle (bijective: 2080 % 8 == 0): consecutive tiles on
    // one XCD share the A panel -> L2 locality.
    int b = blockIdx.x;
    b = (b & 7) * (NTILES / 8) + (b >> 3);

    // triangular decode: b -> (bi <= bj), NBT=64
    int bi = (int)((129.0f - sqrtf(16641.0f - 8.0f * (float)b)) * 0.5f);
    while (NBT * bi - bi * (bi - 1) / 2 > b) --bi;
    while (NBT * (bi + 1) - (bi + 1) * bi / 2 <= b) ++bi;
    const int bj = bi + (b - (NBT * bi - bi * (bi - 1) / 2));
    const int brow = bi * BM;
    const int bcol = bj * BM;
    const bool isdiag = (bi == bj);

    const short* Gs = (const short*)G;

    floatx4 acc[2][2];
    #pragma unroll
    for (int m = 0; m < 2; m++)
        #pragma unroll
        for (int n = 0; n < 2; n++)
            acc[m][n] = (floatx4)0.f;

    // stage one K-tile; source chunk XOR'd so swizzled ds_read reads linear.
    // A tile = 64 rows x 8 chunks(16B) = 512 chunks; 256 threads -> 2 each.
    auto stage = [&](int buf, int k0) {
        #pragma unroll
        for (int r = 0; r < 2; r++) {
            int idx = r * 256 + t;              // 16B chunk id, 0..511
            int row = idx >> 3;                 // tile row 0..63
            int cg = (idx & 7) ^ (row & 7);     // swizzled k-chunk
            gload_lds16(Gs + (size_t)(brow + row) * DIM + k0 + cg * 8,
                        As[buf] + idx * 8);
            if (!isdiag)
                gload_lds16(Gs + (size_t)(bcol + row) * DIM + k0 + cg * 8,
                            Bs[buf] + idx * 8);
        }
    };

    stage(0, 0);
    __syncthreads();
    int cur = 0;
    for (int kt = 0; kt < NK; ++kt) {
        if (kt + 1 < NK) stage(cur ^ 1, (kt + 1) * BK);   // prefetch in flight
        const short* Ab = As[cur];
        const short* Bb = isdiag ? As[cur] : Bs[cur];
        #pragma unroll
        for (int kk = 0; kk < 2; kk++) {
            short8 a[2], bfr[2];
            #pragma unroll
            for (int m = 0; m < 2; m++) {
                int row = wr * 32 + m * 16 + (lane & 15);
                a[m] = *(const short8*)(Ab + row * BK +
                        (((kk * 4 + q) ^ (row & 7)) * 8));
            }
            #pragma unroll
            for (int n = 0; n < 2; n++) {
                int row = wc * 32 + n * 16 + (lane & 15);
                bfr[n] = *(const short8*)(Bb + row * BK +
                        (((kk * 4 + q) ^ (row & 7)) * 8));
            }
            #pragma unroll
            for (int m = 0; m < 2; m++)
                #pragma unroll
                for (int n = 0; n < 2; n++)
                    acc[m][n] = __builtin_amdgcn_mfma_f32_16x16x32_bf16(
                        a[m], bfr[n], acc[m][n], 0, 0, 0);
        }
        __syncthreads();   // drains prefetch (vmcnt) + ds_reads before overwrite
        cur ^= 1;
    }

    // ---- epilogue ----
    // C/D layout: col = lane&15, row = q*4 + reg (m89-verified)
    const int colbase = bcol + wc * 32 + (lane & 15);
    int lc[2];
    #pragma unroll
    for (int n = 0; n < 2; n++) lc[n] = labels[colbase + n * 16];

    float pcr[2] = {0.f, 0.f};   // column partials (row_sum of S^T)
    float pcp[2] = {0.f, 0.f};

    #pragma unroll
    for (int m = 0; m < 2; m++) {
        #pragma unroll
        for (int j = 0; j < 4; j++) {
            const int i = brow + wr * 32 + m * 16 + q * 4 + j;
            const int li = labels[i];
            float pr = 0.f, pp = 0.f;
            #pragma unroll
            for (int n = 0; n < 2; n++) {
                float e = __expf(10.0f * acc[m][n][j]);
                bool dg = (i == colbase + n * 16);     // only on diag tiles
                bool pos = (li == lc[n]) && !dg;
                float er = dg ? 0.f : e;
                float ep = pos ? e : 0.f;
                pr += er;
                pp += ep;
                pcr[n] += er;
                pcp[n] += ep;
            }
            #pragma unroll
            for (int off = 1; off < 16; off <<= 1) {
                pr += __shfl_xor(pr, off);
                pp += __shfl_xor(pp, off);
            }
            if ((lane & 15) == 0) {
                atomicAdd(&row_sum[i], pr);
                atomicAdd(&pos_sum[i], pp);
            }
        }
    }

    if (!isdiag) {
        #pragma unroll
        for (int n = 0; n < 2; n++) {
            pcr[n] += __shfl_xor(pcr[n], 16);
            pcr[n] += __shfl_xor(pcr[n], 32);
            pcp[n] += __shfl_xor(pcp[n], 16);
            pcp[n] += __shfl_xor(pcp[n], 32);
        }
        if (lane < 16) {
            #pragma unroll
            for (int n = 0; n < 2; n++) {
                atomicAdd(&row_sum[colbase + n * 16], pcr[n]);
                atomicAdd(&pos_sum[colbase + n * 16], pcp[n]);
            }
        }
    }

    // ---- last-block-done fused finalize (LDS scratch aliases As/Bs) ----
    int* hist = (int*)&As[0][0];           // 16 ints
    int* slast = ((int*)&As[0][0]) + 16;   // 1 int
    double* red = (double*)&Bs[0][0];      // 12 doubles

    __syncthreads();
    if (t == 0) {
        __threadfence();                   // release: publish atomics
        unsigned int old = atomicAdd(done, 1u);
        *slast = (old == NTILES - 1) ? 1 : 0;
    }
    __syncthreads();
    if (!*slast) return;
    __threadfence();                       // acquire side

    if (t < 16) hist[t] = 0;
    __syncthreads();
    for (int i = t; i < N_SAMPLES; i += 256)
        atomicAdd(&hist[labels[i] & 15], 1);
    __syncthreads();

    double a = 0.0, bb = 0.0, c = 0.0;
    for (int i = t; i < N_SAMPLES; i += 256) {
        int cnt = hist[labels[i] & 15] - 1;
        float rs = __hip_atomic_load(&row_sum[i], __ATOMIC_RELAXED,
                                     __HIP_MEMORY_SCOPE_AGENT);
        float ps = __hip_atomic_load(&pos_sum[i], __ATOMIC_RELAXED,
                                     __HIP_MEMORY_SCOPE_AGENT);
        a -= (double)__logf(rs);
        double inv = 1.0 / (double)cnt;
        bb += inv;
        c += (double)__logf(ps + (float)(N_SAMPLES - cnt)) * inv;
    }
    #pragma unroll
    for (int off = 1; off < 64; off <<= 1) {
        a += __shfl_xor(a, off);
        bb += __shfl_xor(bb, off);
        c += __shfl_xor(c, off);
    }
    if (lane == 0) {
        red[wid] = a; red[4 + wid] = bb; red[8 + wid] = c;
    }
    __syncthreads();
    if (t == 0) {
        double A = 0, B = 0, C = 0;
        #pragma unroll
        for (int w = 0; w < 4; w++) { A += red[w]; B += red[4 + w]; C += red[8 + w]; }
        double res = -(A * B + (double)N_SAMPLES * C) /
                     ((double)N_SAMPLES * (double)N_SAMPLES);
        out[0] = (float)res;
    }
}

// ---------------------------------------------------------------------------
extern "C" void kernel_launch(void* const* d_in, const int* in_sizes, int n_in,
                              void* d_out, int out_size, void* d_ws, size_t ws_size,
                              hipStream_t stream)
{
    const float* F = (const float*)d_in[0];
    const int* labels = (const int*)d_in[1];
    float* out = (float*)d_out;

    char* ws = (char*)d_ws;
    __hip_bfloat16* G = (__hip_bfloat16*)ws;                        // 4 MB
    float* row_sum = (float*)(ws + (size_t)N_SAMPLES * DIM * 2);
    float* pos_sum = row_sum + N_SAMPLES;
    unsigned int* done = (unsigned int*)(pos_sum + N_SAMPLES);

    scl_normalize<<<N_SAMPLES / 8, 512, 0, stream>>>(F, G, row_sum, pos_sum, done);
    scl_gemm_epilogue<<<NTILES, 256, 0, stream>>>(G, labels, row_sum, pos_sum,
                                                  done, out);
}

// Round 8
// 56.454 us; speedup vs baseline: 1.5797x; 1.5797x over previous
//
#include <hip/hip_runtime.h>
#include <hip/hip_bf16.h>

#define N_SAMPLES 4096
#define DIM 512
#define BM 128
#define BK 64
#define NK (DIM / BK)                 // 8 K-steps
#define NBT (N_SAMPLES / BM)          // 32 tiles per dim
#define NTILES (NBT * (NBT + 1) / 2)  // 528 upper-triangle tiles

typedef __attribute__((ext_vector_type(8))) short short8;
typedef __attribute__((ext_vector_type(4))) float floatx4;

__device__ __forceinline__ void gload_lds16(const void* gptr, void* lptr) {
    __builtin_amdgcn_global_load_lds(
        (const __attribute__((address_space(1))) void*)gptr,
        (__attribute__((address_space(3))) void*)lptr, 16, 0, 0);
}

__device__ __forceinline__ short bf16bits(float x) {
    __hip_bfloat16 h = __float2bfloat16(x);
    return *reinterpret_cast<short*>(&h);
}

// ---------------------------------------------------------------------------
// Kernel 1: row L2-normalize fp32 -> bf16 G (one wave per row, no barriers).
// Also zeroes the 4 MB partial-sum arrays (1 float4 per thread) + done2.
// ---------------------------------------------------------------------------
__global__ __launch_bounds__(512) void scl_normalize(
    const float* __restrict__ F, __hip_bfloat16* __restrict__ G,
    float4* __restrict__ partials, unsigned int* __restrict__ done2)
{
    const int t = threadIdx.x;
    const int lane = t & 63;
    const int row = blockIdx.x * 8 + (t >> 6);
    const float4* fr = (const float4*)(F + (size_t)row * DIM);
    float4 va = fr[lane * 2];
    float4 vb = fr[lane * 2 + 1];
    float ss = va.x * va.x + va.y * va.y + va.z * va.z + va.w * va.w +
               vb.x * vb.x + vb.y * vb.y + vb.z * vb.z + vb.w * vb.w;
    #pragma unroll
    for (int off = 1; off < 64; off <<= 1) ss += __shfl_xor(ss, off);
    float inv = ss > 0.f ? 1.0f / sqrtf(ss) : 0.f;
    short8 h;
    h[0] = bf16bits(va.x * inv); h[1] = bf16bits(va.y * inv);
    h[2] = bf16bits(va.z * inv); h[3] = bf16bits(va.w * inv);
    h[4] = bf16bits(vb.x * inv); h[5] = bf16bits(vb.y * inv);
    h[6] = bf16bits(vb.z * inv); h[7] = bf16bits(vb.w * inv);
    ((short8*)((short*)G + (size_t)row * DIM))[lane] = h;
    // zero 4 MB of partials: 512 blk x 512 thr = 262144 float4 = 4 MB exactly
    partials[blockIdx.x * 512 + t] = (float4){0.f, 0.f, 0.f, 0.f};
    if (t == 0 && blockIdx.x == 0) *done2 = 0u;
}

// ---------------------------------------------------------------------------
// Kernel 2: upper-triangle tile (bi<=bj) of S = G*G^T, bf16 MFMA 16x16x32.
// R1 internals restored (the only config measured at 346 TF / 48 ns-per-tile):
// LINEAR gload_lds source, LINEAR ds_read (bank conflicts accepted, m97-style),
// natural blockIdx order, single-buffered 32 KB LDS, 4 waves (2x2) wave-tile
// 64x64. NO atomics: epilogue writes conflict-free partial sums
//   PRow[(bj*2+wc)][i]  (rows),  PCol[(bi*2+wr)][j]  (cols, off-diag mirror)
// reduced by kernel 3. This isolates the R2 bundle (swizzles/remap/atomics)
// that correlates with the 2x per-tile regression.
// ---------------------------------------------------------------------------
__global__ __launch_bounds__(256) void scl_gemm(
    const __hip_bfloat16* __restrict__ G,
    const int* __restrict__ labels,
    float* __restrict__ prow_r, float* __restrict__ prow_p,
    float* __restrict__ pcol_r, float* __restrict__ pcol_p)
{
    __shared__ __align__(16) short As[BM * BK];   // 16 KB
    __shared__ __align__(16) short Bs[BM * BK];   // 16 KB -> 32 KB total

    const int t = threadIdx.x;
    const int lane = t & 63;
    const int q = lane >> 4;            // quarter-group 0..3 (k-chunk)
    const int wid = t >> 6;             // 0..3
    const int wr = wid >> 1;            // wave row 0..1 (64 rows)
    const int wc = wid & 1;             // wave col 0..1 (64 cols)

    // triangular decode from RAW blockIdx (no XCD remap)
    int b = blockIdx.x;
    int bi = (int)((65.0f - sqrtf(4225.0f - 8.0f * (float)b)) * 0.5f);
    while (32 * bi - bi * (bi - 1) / 2 > b) --bi;
    while (32 * (bi + 1) - (bi + 1) * bi / 2 <= b) ++bi;
    const int bj = bi + (b - (32 * bi - bi * (bi - 1) / 2));
    const int brow = bi * BM;
    const int bcol = bj * BM;
    const bool isdiag = (bi == bj);

    const short* Gs = (const short*)G;

    floatx4 acc[4][4];
    #pragma unroll
    for (int m = 0; m < 4; m++)
        #pragma unroll
        for (int n = 0; n < 4; n++)
            acc[m][n] = (floatx4)0.f;

    for (int kt = 0; kt < NK; ++kt) {
        const int k0 = kt * BK;
        // LINEAR staging (R1): lane-linear LDS dest, linear global source
        #pragma unroll
        for (int r = 0; r < 4; r++) {
            int idx = r * 256 + t;              // 16B chunk id, 0..1023
            int row = idx >> 3;                 // tile row 0..127
            int c8  = idx & 7;                  // k-chunk 0..7 (linear!)
            gload_lds16(Gs + (size_t)(brow + row) * DIM + k0 + c8 * 8,
                        As + idx * 8);
            if (!isdiag)
                gload_lds16(Gs + (size_t)(bcol + row) * DIM + k0 + c8 * 8,
                            Bs + idx * 8);
        }
        __syncthreads();                        // drains gload_lds
        const short* Bb = isdiag ? As : Bs;
        #pragma unroll
        for (int kk = 0; kk < 2; kk++) {
            short8 a[4], bfr[4];
            #pragma unroll
            for (int m = 0; m < 4; m++)
                a[m] = *(const short8*)(As +
                        (wr * 64 + m * 16 + (lane & 15)) * BK + kk * 32 + q * 8);
            #pragma unroll
            for (int n = 0; n < 4; n++)
                bfr[n] = *(const short8*)(Bb +
                        (wc * 64 + n * 16 + (lane & 15)) * BK + kk * 32 + q * 8);
            #pragma unroll
            for (int m = 0; m < 4; m++)
                #pragma unroll
                for (int n = 0; n < 4; n++)
                    acc[m][n] = __builtin_amdgcn_mfma_f32_16x16x32_bf16(
                        a[m], bfr[n], acc[m][n], 0, 0, 0);
        }
        __syncthreads();                        // LDS safe to overwrite
    }

    // ---- epilogue: exp + masked sums -> conflict-free partial stores ----
    // C/D layout: col = lane&15, row = q*4 + reg (m89-verified)
    const int colbase = bcol + wc * 64 + (lane & 15);
    int lc[4];
    #pragma unroll
    for (int n = 0; n < 4; n++) lc[n] = labels[colbase + n * 16];

    float pcr[4] = {0.f, 0.f, 0.f, 0.f};   // column partials (mirror rows)
    float pcp[4] = {0.f, 0.f, 0.f, 0.f};

    const int rslot = (bj * 2 + wc) * N_SAMPLES;   // unique per (tile, wave-col)

    #pragma unroll
    for (int m = 0; m < 4; m++) {
        #pragma unroll
        for (int j = 0; j < 4; j++) {
            const int i = brow + wr * 64 + m * 16 + q * 4 + j;
            const int li = labels[i];
            float pr = 0.f, pp = 0.f;
            #pragma unroll
            for (int n = 0; n < 4; n++) {
                float e = __expf(10.0f * acc[m][n][j]);
                bool dg = (i == colbase + n * 16);     // only on diag tiles
                bool pos = (li == lc[n]) && !dg;
                float er = dg ? 0.f : e;
                float ep = pos ? e : 0.f;
                pr += er;
                pp += ep;
                pcr[n] += er;
                pcp[n] += ep;
            }
            #pragma unroll
            for (int off = 1; off < 16; off <<= 1) {
                pr += __shfl_xor(pr, off);
                pp += __shfl_xor(pp, off);
            }
            if ((lane & 15) == 0) {
                prow_r[rslot + i] = pr;        // plain store, slot is unique
                prow_p[rslot + i] = pp;
            }
        }
    }

    if (!isdiag) {
        const int cslot = (bi * 2 + wr) * N_SAMPLES;   // unique per (tile, wave-row)
        #pragma unroll
        for (int n = 0; n < 4; n++) {
            pcr[n] += __shfl_xor(pcr[n], 16);
            pcr[n] += __shfl_xor(pcr[n], 32);
            pcp[n] += __shfl_xor(pcp[n], 16);
            pcp[n] += __shfl_xor(pcp[n], 32);
        }
        if (lane < 16) {
            #pragma unroll
            for (int n = 0; n < 4; n++) {
                pcol_r[cslot + colbase + n * 16] = pcr[n];
                pcol_p[cslot + colbase + n * 16] = pcp[n];
            }
        }
    }
}

// ---------------------------------------------------------------------------
// Kernel 3: finalize. 16 blocks x 256 threads, one thread per row.
// Reads the 64+64 partial slots per row (coalesced: adjacent threads ->
// adjacent addresses), computes per-row log terms, double block-reduce,
// last block combines the 16 block partials.
// ---------------------------------------------------------------------------
__global__ __launch_bounds__(256) void scl_finalize(
    const int* __restrict__ labels,
    const float* __restrict__ prow_r, const float* __restrict__ prow_p,
    const float* __restrict__ pcol_r, const float* __restrict__ pcol_p,
    double* __restrict__ red, unsigned int* __restrict__ done2,
    float* __restrict__ out)
{
    __shared__ int hist[16];
    __shared__ double rbuf[3][4];
    __shared__ int slast;
    const int t = threadIdx.x;
    const int lane = t & 63;
    const int wid = t >> 6;
    const int i = blockIdx.x * 256 + t;

    if (t < 16) hist[t] = 0;
    __syncthreads();
    for (int k = t; k < N_SAMPLES; k += 256)
        atomicAdd(&hist[labels[k] & 15], 1);
    __syncthreads();

    float rs = 0.f, ps = 0.f;
    #pragma unroll 8
    for (int s = 0; s < 2 * NBT; s++) {
        rs += prow_r[s * N_SAMPLES + i] + pcol_r[s * N_SAMPLES + i];
        ps += prow_p[s * N_SAMPLES + i] + pcol_p[s * N_SAMPLES + i];
    }
    const int cnt = hist[labels[i] & 15] - 1;
    double inv = 1.0 / (double)cnt;
    double a = -(double)__logf(rs);
    double bb = inv;
    double c = (double)__logf(ps + (float)(N_SAMPLES - cnt)) * inv;

    #pragma unroll
    for (int off = 1; off < 64; off <<= 1) {
        a += __shfl_xor(a, off);
        bb += __shfl_xor(bb, off);
        c += __shfl_xor(c, off);
    }
    if (lane == 0) { rbuf[0][wid] = a; rbuf[1][wid] = bb; rbuf[2][wid] = c; }
    __syncthreads();
    if (t == 0) {
        double A = rbuf[0][0] + rbuf[0][1] + rbuf[0][2] + rbuf[0][3];
        double B = rbuf[1][0] + rbuf[1][1] + rbuf[1][2] + rbuf[1][3];
        double C = rbuf[2][0] + rbuf[2][1] + rbuf[2][2] + rbuf[2][3];
        red[blockIdx.x * 3 + 0] = A;
        red[blockIdx.x * 3 + 1] = B;
        red[blockIdx.x * 3 + 2] = C;
        __threadfence();                       // release block partials
        unsigned int old = atomicAdd(done2, 1u);
        slast = (old == 15) ? 1 : 0;
    }
    __syncthreads();
    if (!slast) return;
    if (t == 0) {
        double A = 0.0, B = 0.0, C = 0.0;
        for (int k = 0; k < 16; k++) {
            A += __hip_atomic_load(&red[k * 3 + 0], __ATOMIC_RELAXED,
                                   __HIP_MEMORY_SCOPE_AGENT);
            B += __hip_atomic_load(&red[k * 3 + 1], __ATOMIC_RELAXED,
                                   __HIP_MEMORY_SCOPE_AGENT);
            C += __hip_atomic_load(&red[k * 3 + 2], __ATOMIC_RELAXED,
                                   __HIP_MEMORY_SCOPE_AGENT);
        }
        double res = -(A * B + (double)N_SAMPLES * C) /
                     ((double)N_SAMPLES * (double)N_SAMPLES);
        out[0] = (float)res;
    }
}

// ---------------------------------------------------------------------------
extern "C" void kernel_launch(void* const* d_in, const int* in_sizes, int n_in,
                              void* d_out, int out_size, void* d_ws, size_t ws_size,
                              hipStream_t stream)
{
    const float* F = (const float*)d_in[0];
    const int* labels = (const int*)d_in[1];
    float* out = (float*)d_out;

    char* ws = (char*)d_ws;
    __hip_bfloat16* G = (__hip_bfloat16*)ws;                 // [0, 4 MB)
    float* prow_r = (float*)(ws + (4 << 20));                // 1 MB each
    float* prow_p = (float*)(ws + (5 << 20));
    float* pcol_r = (float*)(ws + (6 << 20));
    float* pcol_p = (float*)(ws + (7 << 20));
    double* red = (double*)(ws + (8 << 20));                 // 16*3 doubles
    unsigned int* done2 = (unsigned int*)(ws + (8 << 20) + 512);

    scl_normalize<<<N_SAMPLES / 8, 512, 0, stream>>>(F, G, (float4*)prow_r, done2);
    scl_gemm<<<NTILES, 256, 0, stream>>>(G, labels, prow_r, prow_p,
                                         pcol_r, pcol_p);
    scl_finalize<<<16, 256, 0, stream>>>(labels, prow_r, prow_p, pcol_r,
                                         pcol_p, red, done2, out);
}